// Round 1
// baseline (4120.984 us; speedup 1.0000x reference)
//
#include <hip/hip_runtime.h>

// RNN scan: h_{t+1} = 0.5 h_t + 0.5 (tanh(h_t) @ wrec^T + x_t@wi + brec) + sqrt(dt)*std * n_t
//           out_t   = tanh(h_{t+1}) @ wo
// B=128,T=1024,I=64,H=512,O=64. Latency-bound sequential scan.
// Design: 64 blocks = 8 batch-groups(16) x 8 hidden-slices(64 cols).
//   - wrec bf16 slice resident in VGPRs (16 B-frags = 64 VGPR/lane)
//   - per-step all-gather of tanh(h) slices via LLC (sc0 sc1 stores, frag-ordered),
//     agent-scope release counters, relaxed spin
//   - h state lives in MFMA C/D-layout registers (4 f32/lane)
//   - readout K-split 2-way across block pairs, fp32 atomicAdd (2-way = deterministic)

#define TSTEPS 1024
#define HDIM   512
#define IDIM   64
#define ODIM   64
#define NSCALE 0.035355339059327376f  /* sqrt(0.5)*0.05 */

typedef short bf16x8  __attribute__((ext_vector_type(8)));
typedef float f32x4   __attribute__((ext_vector_type(4)));
typedef int   int4v   __attribute__((ext_vector_type(4)));
typedef short short4v __attribute__((ext_vector_type(4)));

__device__ __forceinline__ unsigned short f2bf(float f){
  unsigned u = __float_as_uint(f);
  u = (u + 0x7fffu + ((u >> 16) & 1u)) >> 16;  // RN-even, no NaN inputs here
  return (unsigned short)u;
}
__device__ __forceinline__ float tanh_fast(float x){
  float e = __expf(2.0f * x);           // overflow->inf gives tanh=+1, underflow->0 gives -1
  return 1.0f - 2.0f / (e + 1.0f);
}
__device__ __forceinline__ int4v load16_llc(const void* p){
  int4v r;
  asm volatile("global_load_dwordx4 %0, %1, off sc0 sc1" : "=v"(r) : "v"(p) : "memory");
  return r;
}
__device__ __forceinline__ void store2_llc(void* p, unsigned v){
  asm volatile("global_store_short %0, %1, off sc0 sc1" :: "v"(p), "v"(v) : "memory");
}

// ---- phase 1: weight conversion / transposes (bf16) ----
__global__ void prep_kernel(const float* __restrict__ wi, const float* __restrict__ wrec,
                            const float* __restrict__ wo,
                            unsigned short* __restrict__ wrecb,
                            unsigned short* __restrict__ wiT,
                            unsigned short* __restrict__ woT){
  int i = blockIdx.x * 256 + threadIdx.x;
  if (i < HDIM*HDIM){
    wrecb[i] = f2bf(wrec[i]);                       // [j][k] row-major (B[k][j]=wrec[j][k])
  } else if (i < HDIM*HDIM + HDIM*IDIM){
    int q = i - HDIM*HDIM; int j = q >> 6, ii = q & 63;
    wiT[q] = f2bf(wi[ii*HDIM + j]);                 // wiT[j][i]
  } else if (i < HDIM*HDIM + HDIM*IDIM + ODIM*HDIM){
    int q = i - HDIM*HDIM - HDIM*IDIM; int o = q >> 9, k = q & 511;
    woT[q] = f2bf(wo[k*ODIM + o]);                  // woT[o][k]
  }
}

// ---- phase 2: the sequential scan ----
__global__ __launch_bounds__(256, 1) void rnn_scan(
    const float* __restrict__ input, const float* __restrict__ noise,
    const float* __restrict__ brec,  const float* __restrict__ h0,
    const unsigned short* __restrict__ wrecb,
    const unsigned short* __restrict__ wiT,
    const unsigned short* __restrict__ woT,
    unsigned short* __restrict__ tanhbuf,   // [2 parity][8 group][16KB frag-ordered]
    unsigned int*  __restrict__ flags,      // [8 group][2 parity] stride-32 uints
    float* __restrict__ out)
{
  __shared__ short lds_tanh[8192];   // 16KB: gathered tanh(h_t), frag-linear
  __shared__ short in_tile[1024];    // 2KB: input_t bf16 [16][64], XOR-swizzled
  __shared__ float lds_ro[4][256];   // readout partials per wave

  const int tid  = threadIdx.x;
  const int l    = tid & 63;
  const int w    = tid >> 6;          // wave 0..3
  const int g    = blockIdx.x >> 3;   // batch group 0..7
  const int s    = blockIdx.x & 7;    // hidden slice 0..7
  const int b0   = g * 16;
  const int row  = l & 15;
  const int kgrp = l >> 4;

  const int jcol = s*64 + w*16 + row; // this lane's hidden column (N of rec, also its published k)
  const int ot   = s & 3;             // readout o-tile
  const int kh   = s >> 2;            // readout k-half
  const int ocol = ot*16 + row;

  // Resident B fragments (registers). MFMA 16x16x32 bf16 layout:
  //   A: row=l&15, k=8*(l>>4)+i (contiguous 8 bf16 = one b128)
  //   B: col=l&15, k=8*(l>>4)+i ; C/D: col=l&15, row=4*(l>>4)+r
  bf16x8 Brec[16];
#pragma unroll
  for (int kt = 0; kt < 16; ++kt)
    Brec[kt] = *(const bf16x8*)(wrecb + jcol*HDIM + kt*32 + kgrp*8);
  bf16x8 Bwi[2];
#pragma unroll
  for (int u = 0; u < 2; ++u)
    Bwi[u] = *(const bf16x8*)(wiT + jcol*IDIM + u*32 + kgrp*8);
  bf16x8 Bwo[2];
#pragma unroll
  for (int u = 0; u < 2; ++u)
    Bwo[u] = *(const bf16x8*)(woT + ocol*HDIM + (kh*8 + 2*w + u)*32 + kgrp*8);

  const float brec_l = brec[jcol];
  const float h0_l   = h0[jcol];
  float h[4] = {h0_l, h0_l, h0_l, h0_l};

  const float* nbase[4];
  int pub_off[4];
#pragma unroll
  for (int r = 0; r < 4; ++r){
    int m = kgrp*4 + r;                                   // batch row of this acc element
    nbase[r] = noise + ((long)(b0 + m) * TSTEPS) * HDIM + jcol;
    // frag-ordered position of element (m, k=jcol): kt=k>>5, lane'=m+((k>>3)&3)*16, byte=(k&7)*2
    pub_off[r] = (jcol >> 5)*1024 + (m + ((jcol >> 3) & 3)*16)*16 + (jcol & 7)*2;
  }

  char* const slotA = (char*)tanhbuf + (0*8 + g)*16384;   // parity 0
  char* const slotB = (char*)tanhbuf + (1*8 + g)*16384;   // parity 1
  unsigned int* const flgA = flags + (g*2 + 0)*32;
  unsigned int* const flgB = flags + (g*2 + 1)*32;

  const f32x4 zero4 = {0.f, 0.f, 0.f, 0.f};

  auto stage_input = [&](int tt){
    int m = tid >> 4, i0 = (tid & 15) * 4;
    const float* src = input + ((long)(b0 + m) * TSTEPS + tt) * IDIM + i0;
    float4 v = *(const float4*)src;
    short4v pk;
    pk.x = (short)f2bf(v.x); pk.y = (short)f2bf(v.y);
    pk.z = (short)f2bf(v.z); pk.w = (short)f2bf(v.w);
    int byt = (m*128 + i0*2) ^ ((m & 7) << 4);           // XOR swizzle, bank-safe
    *(short4v*)((char*)in_tile + byt) = pk;
  };

  auto xw_mfma = [&]() -> f32x4 {
    f32x4 a = zero4;
#pragma unroll
    for (int u = 0; u < 2; ++u){
      int byt = (row*128 + u*64 + kgrp*16) ^ ((row & 7) << 4);
      bf16x8 af = *(const bf16x8*)((const char*)in_tile + byt);
      a = __builtin_amdgcn_mfma_f32_16x16x32_bf16(af, Bwi[u], a, 0, 0, 0);
    }
    return a;
  };

  auto gather = [&](const char* sl){
    int4v q0 = load16_llc(sl + tid*16);
    int4v q1 = load16_llc(sl + tid*16 + 4096);
    int4v q2 = load16_llc(sl + tid*16 + 8192);
    int4v q3 = load16_llc(sl + tid*16 + 12288);
    asm volatile("s_waitcnt vmcnt(0)" ::: "memory");
    int4v* dst = (int4v*)lds_tanh;
    dst[tid] = q0; dst[tid + 256] = q1; dst[tid + 512] = q2; dst[tid + 768] = q3;
  };

  // ---- prologue: xw_0 and publish tanh(h_0) ----
  stage_input(0);
  __syncthreads();
  f32x4 acc_xw = xw_mfma();
  {
    unsigned tb = (unsigned)f2bf(tanh_fast(h0_l));
#pragma unroll
    for (int r = 0; r < 4; ++r) store2_llc(slotA + pub_off[r], tb);
    asm volatile("s_waitcnt vmcnt(0)" ::: "memory");
    __syncthreads();
    if (tid == 0) __hip_atomic_fetch_add(flgA, 1u, __ATOMIC_RELEASE, __HIP_MEMORY_SCOPE_AGENT);
  }

  // ---- main scan. iter t: gather tanh(h_t); compute h_{t+1}; publish; readout out_{t-1} ----
  for (int t = 0; t <= TSTEPS; ++t){
    const bool compute = (t < TSTEPS);
    const int p = t & 1;
    char* slp = p ? slotB : slotA;            // slot holding tanh(h_t)
    char* slq = p ? slotA : slotB;            // slot for tanh(h_{t+1})
    unsigned int* flp = p ? flgB : flgA;
    unsigned int* flq = p ? flgA : flgB;

    float nz[4] = {0.f, 0.f, 0.f, 0.f};
    if (compute){
#pragma unroll
      for (int r = 0; r < 4; ++r) nz[r] = nbase[r][(long)t * HDIM];  // prefetch, hides under spin
    }

    if (tid == 0){
      const unsigned tgt = 8u * ((unsigned)(t >> 1) + 1u);
      while (__hip_atomic_load(flp, __ATOMIC_RELAXED, __HIP_MEMORY_SCOPE_AGENT) < tgt)
        __builtin_amdgcn_s_sleep(1);
    }
    __syncthreads();
    gather(slp);
    __syncthreads();

    if (compute){
      f32x4 acc[4];
      acc[0] = acc_xw; acc[1] = zero4; acc[2] = zero4; acc[3] = zero4;
      const bf16x8* At = (const bf16x8*)lds_tanh;
#pragma unroll
      for (int kt = 0; kt < 16; ++kt)
        acc[kt & 3] = __builtin_amdgcn_mfma_f32_16x16x32_bf16(
            At[kt*64 + l], Brec[kt], acc[kt & 3], 0, 0, 0);

#pragma unroll
      for (int r = 0; r < 4; ++r){
        float rec = acc[0][r] + acc[1][r] + acc[2][r] + acc[3][r] + brec_l;
        float hn  = 0.5f*h[r] + 0.5f*rec + NSCALE*nz[r];
        h[r] = hn;
        unsigned tb = (unsigned)f2bf(tanh_fast(hn));
        store2_llc(slq + pub_off[r], tb);
      }
      asm volatile("s_waitcnt vmcnt(0)" ::: "memory");   // sc0sc1 stores complete at LLC
    }
    __syncthreads();
    if (compute && tid == 0)
      __hip_atomic_fetch_add(flq, 1u, __ATOMIC_RELEASE, __HIP_MEMORY_SCOPE_AGENT);

    // readout out_{t-1} = tanh(h_t) @ wo  (uses gathered lds_tanh; off critical path)
    if (t >= 1){
      const bf16x8* At = (const bf16x8*)lds_tanh;
      const int rk = kh*8 + 2*w;
      f32x4 ro = zero4;
      ro = __builtin_amdgcn_mfma_f32_16x16x32_bf16(At[rk*64 + l],       Bwo[0], ro, 0, 0, 0);
      ro = __builtin_amdgcn_mfma_f32_16x16x32_bf16(At[(rk + 1)*64 + l], Bwo[1], ro, 0, 0, 0);
#pragma unroll
      for (int r = 0; r < 4; ++r) lds_ro[w][(kgrp*4 + r)*16 + row] = ro[r];
    }
    if (t + 1 < TSTEPS) stage_input(t + 1);
    __syncthreads();
    if (t >= 1){
      float v = lds_ro[0][tid] + lds_ro[1][tid] + lds_ro[2][tid] + lds_ro[3][tid];
      int m = tid >> 4, o = tid & 15;
      // k-half partial: exactly 2 atomic adds per element onto 0 -> deterministic
      atomicAdd(out + ((long)(b0 + m)*TSTEPS + (t - 1))*ODIM + ot*16 + o, v);
    }
    if (t + 1 < TSTEPS) acc_xw = xw_mfma();   // overlaps peers' spin window
  }
}

extern "C" void kernel_launch(void* const* d_in, const int* in_sizes, int n_in,
                              void* d_out, int out_size, void* d_ws, size_t ws_size,
                              hipStream_t stream){
  (void)in_sizes; (void)n_in; (void)ws_size;
  const float* input = (const float*)d_in[0];
  const float* wi    = (const float*)d_in[1];
  const float* wrec  = (const float*)d_in[2];
  const float* wo    = (const float*)d_in[3];
  const float* brec  = (const float*)d_in[4];
  const float* h0    = (const float*)d_in[5];
  const float* noise = (const float*)d_in[6];
  float* out = (float*)d_out;

  char* ws = (char*)d_ws;
  unsigned short* wrecb = (unsigned short*)(ws);            // 512KB
  unsigned short* wiT   = (unsigned short*)(ws + 524288);   // 64KB
  unsigned short* woT   = (unsigned short*)(ws + 589824);   // 64KB
  unsigned short* tanhb = (unsigned short*)(ws + 655360);   // 256KB exchange
  unsigned int*   flags = (unsigned int*)  (ws + 917504);   // 2KB counters

  hipMemsetAsync(d_out, 0, (size_t)out_size * sizeof(float), stream);
  hipMemsetAsync(flags, 0, 2048, stream);
  prep_kernel<<<1280, 256, 0, stream>>>(wi, wrec, wo, wrecb, wiT, woT);
  rnn_scan<<<64, 256, 0, stream>>>(input, noise, brec, h0, wrecb, wiT, woT, tanhb, flags, out);
}

// Round 5
// 2911.900 us; speedup vs baseline: 1.4152x; 1.4152x over previous
//
#include <hip/hip_runtime.h>

// RNN scan, latency-bound: 64 blocks = 8 groups(batch 16) x 8 hidden slices(64 cols).
// v4 = v3 + per-GROUP flags (v3 bug: all groups shared one flag array -> early release
//      by fast groups -> stale exchange reads -> absmax 0.17).
// Structure: ALL cross-block traffic at LLC scope (sc0 sc1, v1-proven hang-proof).
//   Swapped-operand MFMA (D[j][m]) -> per-lane 8B register publish (no LDS staging,
//   one barrier/step). Per-wave flags ordered by each wave's own vmcnt(0).
//   Dedicated poller wave (wave 4) + LDS mailbox. Full-K single-writer readout.

#define TSTEPS 1024
#define HDIM   512
#define IDIM   64
#define ODIM   64
#define NSCALE 0.035355339059327376f  /* sqrt(0.5)*0.05 */

typedef short bf16x8  __attribute__((ext_vector_type(8)));
typedef float f32x4   __attribute__((ext_vector_type(4)));
typedef int   int4v   __attribute__((ext_vector_type(4)));
typedef int   int2v   __attribute__((ext_vector_type(2)));
typedef short short4v __attribute__((ext_vector_type(4)));

__device__ __forceinline__ unsigned short f2bf(float f){
  unsigned u = __float_as_uint(f);
  u = (u + 0x7fffu + ((u >> 16) & 1u)) >> 16;  // RN-even; inputs never NaN
  return (unsigned short)u;
}
__device__ __forceinline__ float tanh_fast(float x){
  float e = __expf(2.0f * x);          // overflow->inf gives +1, underflow->0 gives -1
  return 1.0f - 2.0f / (e + 1.0f);
}

template<int OFF>
__device__ __forceinline__ int4v g_load16(const char* p){
  int4v r;
  asm volatile("global_load_dwordx4 %0, %1, off offset:%2 sc0 sc1"
               : "=v"(r) : "v"(p), "n"(OFF) : "memory");
  return r;
}
__device__ __forceinline__ void g_store8(void* p, int2v v){
  asm volatile("global_store_dwordx2 %0, %1, off sc0 sc1" :: "v"(p), "v"(v) : "memory");
}
__device__ __forceinline__ void g_store4(void* p, unsigned v){
  asm volatile("global_store_dword %0, %1, off sc0 sc1" :: "v"(p), "v"(v) : "memory");
}

// ---- phase 1: weight conversion / transposes (bf16) ----
__global__ void prep_kernel(const float* __restrict__ wi, const float* __restrict__ wrec,
                            const float* __restrict__ wo,
                            unsigned short* __restrict__ wrecb,
                            unsigned short* __restrict__ wiT,
                            unsigned short* __restrict__ woT){
  int i = blockIdx.x * 256 + threadIdx.x;
  if (i < HDIM*HDIM){
    wrecb[i] = f2bf(wrec[i]);                       // [j][k]
  } else if (i < HDIM*HDIM + HDIM*IDIM){
    int q = i - HDIM*HDIM; int j = q >> 6, ii = q & 63;
    wiT[q] = f2bf(wi[ii*HDIM + j]);                 // wiT[j][i]
  } else if (i < HDIM*HDIM + HDIM*IDIM + ODIM*HDIM){
    int q = i - HDIM*HDIM - HDIM*IDIM; int o = q >> 9, k = q & 511;
    woT[q] = f2bf(wo[k*ODIM + o]);                  // woT[o][k]
  }
}

// ---- phase 2: sequential scan ----
__global__ __launch_bounds__(320, 1) void rnn_scan(
    const float* __restrict__ input, const float* __restrict__ noise,
    const float* __restrict__ brec,  const float* __restrict__ h0,
    const unsigned short* __restrict__ wrecb,
    const unsigned short* __restrict__ wiT,
    const unsigned short* __restrict__ woT,
    unsigned short* __restrict__ tanhbuf,   // [2 parity][8 group][16KB frag-ordered]
    unsigned int*  __restrict__ flags,      // [8 group][2 parity][32] per-wave flags
    float* __restrict__ out)
{
  __shared__ __align__(16) short in_tile[2][1024];  // 4KB dbuf: input_t bf16 [16][64] swizzled
  __shared__ float lds_ro[2][4][256];               // 8KB dbuf: readout partials per wave
  __shared__ volatile int mbox[2];                  // mailbox: max released step per parity

  const int tid = threadIdx.x;
  const int bid = blockIdx.x;
  const int g   = bid & 7;     // batch group
  const int s   = bid >> 3;    // hidden slice
  const int l   = tid & 63;
  const int w   = tid >> 6;    // wave 0..4

  if (tid == 0){ mbox[0] = 0; mbox[1] = 0; }

  char* const slot0 = (char*)tanhbuf + (0*8 + g)*16384;
  char* const slot1 = (char*)tanhbuf + (1*8 + g)*16384;
  unsigned int* const gflags = flags + g*64;        // this group's [2][32] flags

  if (w < 4){
    // ================= compute waves =================
    const int lr = l & 15, kg = l >> 4;
    const int b0 = g * 16;
    const int jrow = s*64 + w*16 + lr;     // A-operand row (j) for resident fragments

    bf16x8 Arec[16];
#pragma unroll
    for (int kt = 0; kt < 16; ++kt)
      Arec[kt] = *(const bf16x8*)(wrecb + jrow*HDIM + kt*32 + kg*8);
    bf16x8 Awi[2];
#pragma unroll
    for (int u = 0; u < 2; ++u)
      Awi[u] = *(const bf16x8*)(wiT + jrow*IDIM + u*32 + kg*8);
    bf16x8 Awo[4];
    if (s < 4){
      const int ocol = s*16 + lr;
#pragma unroll
      for (int u = 0; u < 4; ++u)
        Awo[u] = *(const bf16x8*)(woT + ocol*HDIM + (w*4 + u)*32 + kg*8);
    }

    // D[j][m] layout: lane holds m = lr (fixed), j = j0 + r, r=0..3 (contiguous!)
    const int j0 = s*64 + w*16 + 4*kg;
    const f32x4 brec4 = *(const f32x4*)(brec + j0);
    const f32x4 h04   = *(const f32x4*)(h0 + j0);
    float h[4] = {h04[0], h04[1], h04[2], h04[3]};

    const float* nbase = noise + ((long)(b0 + lr))*TSTEPS*HDIM + j0;
    // exchange-fragment position of this lane's 8B chunk (j0..j0+3, m=lr):
    const int pub_off = s*2048 + (w>>1)*1024
                      + (lr + 16*((w&1)*2 + (kg>>1)))*16 + (kg&1)*8;

    const f32x4 zero4 = {0.f, 0.f, 0.f, 0.f};

    auto stage_input = [&](int tt, int bufi){
      int m = tid >> 4, i0 = (tid & 15) * 4;
      const float* src = input + ((long)(b0 + m) * TSTEPS + tt) * IDIM + i0;
      float4 v = *(const float4*)src;
      short4v pk;
      pk.x = (short)f2bf(v.x); pk.y = (short)f2bf(v.y);
      pk.z = (short)f2bf(v.z); pk.w = (short)f2bf(v.w);
      int byt = (m*128 + i0*2) ^ ((m & 7) << 4);
      *(short4v*)((char*)in_tile[bufi] + byt) = pk;
    };
    auto xw_mfma = [&](int bufi) -> f32x4 {
      f32x4 a = zero4;
#pragma unroll
      for (int u = 0; u < 2; ++u){
        int byt = (lr*128 + u*64 + kg*16) ^ ((lr & 7) << 4);
        bf16x8 bfv = *(const bf16x8*)((const char*)in_tile[bufi] + byt);
        a = __builtin_amdgcn_mfma_f32_16x16x32_bf16(Awi[u], bfv, a, 0, 0, 0);
      }
      return a;
    };
    auto publish = [&](char* slq, float t0, float t1, float t2, float t3){
      int2v v;
      v.x = (int)((unsigned)f2bf(t0) | ((unsigned)f2bf(t1) << 16));
      v.y = (int)((unsigned)f2bf(t2) | ((unsigned)f2bf(t3) << 16));
      g_store8(slq + pub_off, v);
    };

    // ---- prologue: publish tanh(h0), flag(1), stage input0, xw0 ----
    f32x4 nz4 = *(const f32x4*)nbase;
    publish(slot0, tanh_fast(h04[0]), tanh_fast(h04[1]),
                   tanh_fast(h04[2]), tanh_fast(h04[3]));
    asm volatile("s_waitcnt vmcnt(0)" ::: "memory");
    if (l == 0) g_store4(gflags + (s*4 + w), 1u);
    stage_input(0, 0);
    __syncthreads();                                  // B_pro
    f32x4 acc_xw = xw_mfma(0);

    // ---- main scan: one barrier per step ----
    for (int t = 0; t <= TSTEPS; ++t){
      const bool compute = (t < TSTEPS);
      const int p = t & 1;
      const char* slp = p ? slot1 : slot0;

      while (mbox[p] < t + 1) {}                      // released by poller wave

      // gather all 16 B-frags of tanh(h_t) straight into registers
      const char* gb0 = slp + l*16;
      const char* gb1 = gb0 + 4096;
      const char* gb2 = gb0 + 8192;
      const char* gb3 = gb0 + 12288;
      int4v g0  = g_load16<0>(gb0),  g1  = g_load16<1024>(gb0),
            g2  = g_load16<2048>(gb0), g3 = g_load16<3072>(gb0);
      int4v g4  = g_load16<0>(gb1),  g5  = g_load16<1024>(gb1),
            g6  = g_load16<2048>(gb1), g7 = g_load16<3072>(gb1);
      int4v g8  = g_load16<0>(gb2),  g9  = g_load16<1024>(gb2),
            g10 = g_load16<2048>(gb2), g11 = g_load16<3072>(gb2);
      int4v g12 = g_load16<0>(gb3),  g13 = g_load16<1024>(gb3),
            g14 = g_load16<2048>(gb3), g15 = g_load16<3072>(gb3);
      asm volatile("s_waitcnt vmcnt(0)" ::: "memory");
      __builtin_amdgcn_sched_barrier(0);

      if (compute){
        f32x4 a0 = acc_xw, a1 = zero4, a2 = zero4, a3 = zero4;
#define MF(gv, kt, ac) ac = __builtin_amdgcn_mfma_f32_16x16x32_bf16(Arec[kt], __builtin_bit_cast(bf16x8, gv), ac, 0, 0, 0)
        MF(g0,0,a0);   MF(g1,1,a1);   MF(g2,2,a2);   MF(g3,3,a3);
        MF(g4,4,a0);   MF(g5,5,a1);   MF(g6,6,a2);   MF(g7,7,a3);
        MF(g8,8,a0);   MF(g9,9,a1);   MF(g10,10,a2); MF(g11,11,a3);
        MF(g12,12,a0); MF(g13,13,a1); MF(g14,14,a2); MF(g15,15,a3);
#undef MF
        float tb[4];
#pragma unroll
        for (int r = 0; r < 4; ++r){
          float rec = a0[r] + a1[r] + a2[r] + a3[r] + brec4[r];
          float hn  = 0.5f*h[r] + 0.5f*rec + NSCALE*nz4[r];
          h[r] = hn;
          tb[r] = tanh_fast(hn);
        }
        publish(p ? slot0 : slot1, tb[0], tb[1], tb[2], tb[3]);
        asm volatile("s_waitcnt vmcnt(0)" ::: "memory");  // this wave's stores at LLC
        if (l == 0) g_store4(gflags + ((t+1)&1)*32 + s*4 + w, (unsigned)(t + 2));
        if (t + 1 < TSTEPS)                               // off critical path
          nz4 = *(const f32x4*)(nbase + (long)(t + 1) * HDIM);
      }

      // readout out_{t-1} = tanh(h_t) @ wo — slices 0..3, K split across 4 waves
      if (t >= 1 && s < 4){
        f32x4 ro = zero4;
#define RO(gv, u) ro = __builtin_amdgcn_mfma_f32_16x16x32_bf16(Awo[u], __builtin_bit_cast(bf16x8, gv), ro, 0, 0, 0)
        if (w == 0){ RO(g0,0);  RO(g1,1);  RO(g2,2);  RO(g3,3); }
        else if (w == 1){ RO(g4,0);  RO(g5,1);  RO(g6,2);  RO(g7,3); }
        else if (w == 2){ RO(g8,0);  RO(g9,1);  RO(g10,2); RO(g11,3); }
        else            { RO(g12,0); RO(g13,1); RO(g14,2); RO(g15,3); }
#undef RO
#pragma unroll
        for (int r = 0; r < 4; ++r)
          lds_ro[t & 1][w][(4*kg + r)*16 + lr] = ro[r];   // D[o][m]: o_loc=4kg+r, m=lr
      }
      if (t + 1 < TSTEPS) stage_input(t + 1, (t + 1) & 1);
      __syncthreads();                                    // B2 (the only per-step barrier)
      if (t >= 1 && s < 4){
        const int idx = (tid & 15)*16 + (tid >> 4);       // o_loc = tid&15, m = tid>>4
        float v = lds_ro[t & 1][0][idx] + lds_ro[t & 1][1][idx]
                + lds_ro[t & 1][2][idx] + lds_ro[t & 1][3][idx];
        out[(((long)(b0 + (tid >> 4)))*TSTEPS + (t - 1))*ODIM + s*16 + (tid & 15)] = v;
      }
      if (t + 1 < TSTEPS) acc_xw = xw_mfma((t + 1) & 1);
    }
  } else {
    // ================= poller wave (wave 4) =================
    auto pollto = [&](int q, int tgt){
      const unsigned int* fp = gflags + q*32 + (l & 31);
      for (;;){
        unsigned a;
        asm volatile("global_load_dword %0, %1, off sc0 sc1\n\t"
                     "s_waitcnt vmcnt(0)"
                     : "=v"(a) : "v"(fp) : "memory");
        int m = (int)a;
#pragma unroll
        for (int d = 1; d < 32; d <<= 1){
          int o = __shfl_xor(m, d); m = (o < m) ? o : m;
        }
        if (m >= tgt){ if (l == 0) mbox[q] = m; break; }
      }
    };
    __syncthreads();                                      // B_pro
    pollto(0, 1);
    for (int t = 0; t <= TSTEPS; ++t){
      if (t < TSTEPS) pollto((t + 1) & 1, t + 2);
      __syncthreads();                                    // B2_t
    }
  }
}

extern "C" void kernel_launch(void* const* d_in, const int* in_sizes, int n_in,
                              void* d_out, int out_size, void* d_ws, size_t ws_size,
                              hipStream_t stream){
  (void)in_sizes; (void)n_in; (void)ws_size; (void)out_size;
  const float* input = (const float*)d_in[0];
  const float* wi    = (const float*)d_in[1];
  const float* wrec  = (const float*)d_in[2];
  const float* wo    = (const float*)d_in[3];
  const float* brec  = (const float*)d_in[4];
  const float* h0    = (const float*)d_in[5];
  const float* noise = (const float*)d_in[6];
  float* out = (float*)d_out;

  char* ws = (char*)d_ws;
  unsigned short* wrecb = (unsigned short*)(ws);            // 512KB
  unsigned short* wiT   = (unsigned short*)(ws + 524288);   // 64KB
  unsigned short* woT   = (unsigned short*)(ws + 589824);   // 64KB
  unsigned short* tanhb = (unsigned short*)(ws + 655360);   // 256KB exchange
  unsigned int*   flags = (unsigned int*)  (ws + 917504);   // 2KB: [8 grp][2 par][32]

  hipMemsetAsync(ws + 917504, 0, 2048, stream);
  prep_kernel<<<1280, 256, 0, stream>>>(wi, wrec, wo, wrecb, wiT, woT);
  rnn_scan<<<64, 320, 0, stream>>>(input, noise, brec, h0, wrecb, wiT, woT,
                                   tanhb, flags, out);
}